// Round 7
// baseline (404.044 us; speedup 1.0000x reference)
//
#include <hip/hip_runtime.h>

typedef __attribute__((ext_vector_type(4))) float f32x4;
typedef __attribute__((ext_vector_type(8))) short short8;
typedef __attribute__((ext_vector_type(8))) __bf16 bf16x8;
typedef __attribute__((ext_vector_type(4))) unsigned int u32x4;
typedef __attribute__((ext_vector_type(4))) unsigned short u16x4;
typedef unsigned short u16;
typedef unsigned int u32;

#define NB 2
#define S_LEN 4096
#define NHD 8
#define HID 512

__device__ __forceinline__ u16 f2bf(float f) {
  u32 u = __builtin_bit_cast(u32, f);
  u += 0x7fffu + ((u >> 16) & 1u);   // round-to-nearest-even
  return (u16)(u >> 16);
}

// MFMA wrapper hedged over the two plausible builtin signatures (V8s vs V8y).
template <typename V>
static __device__ __forceinline__ auto mfma_imp(V a, V b, f32x4 c, int)
    -> decltype(__builtin_amdgcn_mfma_f32_16x16x32_bf16(a, b, c, 0, 0, 0)) {
  return __builtin_amdgcn_mfma_f32_16x16x32_bf16(a, b, c, 0, 0, 0);
}
template <typename V>
static __device__ __forceinline__ f32x4 mfma_imp(V a, V b, f32x4 c, long) {
  return __builtin_amdgcn_mfma_f32_16x16x32_bf16(
      __builtin_bit_cast(bf16x8, a), __builtin_bit_cast(bf16x8, b), c, 0, 0, 0);
}
static __device__ __forceinline__ f32x4 mfma_bf16(short8 a, short8 b, f32x4 c) {
  return mfma_imp(a, b, c, 0);
}

// Raw workgroup barrier that does NOT drain vmcnt: own LDS ops flushed
// (lgkmcnt 0), scheduler pinned (rule 18), then s_barrier. Global loads and
// the nontemporal W-store stream stay in flight across it.
#define WG_BARRIER()                                        \
  do {                                                      \
    asm volatile("s_waitcnt lgkmcnt(0)" ::: "memory");      \
    __builtin_amdgcn_sched_barrier(0);                      \
    __builtin_amdgcn_s_barrier();                           \
    __builtin_amdgcn_sched_barrier(0);                      \
  } while (0)

// ---------------------------------------------------------------------------
// Fused projection GEMM (Q, K, V in one launch via blockIdx.z):
// C[i][j] = sum_k X[i][k] * W[j][k] + bias[j], scaled, ->bf16
// z==0 (Q): out [(b*8+h)][s][64], scale 0.125 (1/sqrt(64) folded in)
// z==1 (K): out [(b*8+h)][s][64]
// z==2 (V): out [(b*8+h)][64][s]  (V^T so PV B-operand is contiguous)
// ---------------------------------------------------------------------------
__global__ __launch_bounds__(256, 2) void proj_kernel(
    const float* __restrict__ Xq, const float* __restrict__ Xk,
    const float* __restrict__ Xv, const float* __restrict__ Wq,
    const float* __restrict__ Wk, const float* __restrict__ Wv,
    const float* __restrict__ bq_, const float* __restrict__ bk_,
    const float* __restrict__ bv_, u16* __restrict__ oq,
    u16* __restrict__ ok, u16* __restrict__ ov)
{
  __shared__ u16 Al[128 * 64];
  __shared__ u16 Bl[128 * 64];
  const int z = blockIdx.z;
  const float* X = (z == 0) ? Xq : (z == 1) ? Xk : Xv;
  const float* W = (z == 0) ? Wq : (z == 1) ? Wk : Wv;
  const float* bias = (z == 0) ? bq_ : (z == 1) ? bk_ : bv_;
  u16* out = (z == 0) ? oq : (z == 1) ? ok : ov;
  const int transposeOut = (z == 2);
  const float scale = (z == 0) ? 0.125f : 1.0f;

  const int tid = threadIdx.x;
  const int lane = tid & 63;
  const int wid = tid >> 6;
  const int wr = (wid >> 1) << 6;
  const int wc = (wid & 1) << 6;
  const int bm = blockIdx.x << 7;
  const int bn = blockIdx.y << 7;

  f32x4 acc[4][4] = {};

#pragma unroll 1
  for (int k0 = 0; k0 < HID; k0 += 64) {
    __syncthreads();
#pragma unroll
    for (int i = 0; i < 4; ++i) {
      const int idx = i * 256 + tid;
      const int row = idx >> 3;     // 8 chunks of 8 elems per 64-wide row
      const int c = idx & 7;
      const int off = (row * 128 + c * 16) ^ ((row & 7) << 4);
      const float* ga = X + (size_t)(bm + row) * HID + k0 + c * 8;
      f32x4 a0 = *(const f32x4*)ga;
      f32x4 a1 = *(const f32x4*)(ga + 4);
      short8 pa;
      pa[0] = (short)f2bf(a0[0]); pa[1] = (short)f2bf(a0[1]);
      pa[2] = (short)f2bf(a0[2]); pa[3] = (short)f2bf(a0[3]);
      pa[4] = (short)f2bf(a1[0]); pa[5] = (short)f2bf(a1[1]);
      pa[6] = (short)f2bf(a1[2]); pa[7] = (short)f2bf(a1[3]);
      *(short8*)((char*)Al + off) = pa;
      const float* gb = W + (size_t)(bn + row) * HID + k0 + c * 8;
      f32x4 b0 = *(const f32x4*)gb;
      f32x4 b1 = *(const f32x4*)(gb + 4);
      short8 pb;
      pb[0] = (short)f2bf(b0[0]); pb[1] = (short)f2bf(b0[1]);
      pb[2] = (short)f2bf(b0[2]); pb[3] = (short)f2bf(b0[3]);
      pb[4] = (short)f2bf(b1[0]); pb[5] = (short)f2bf(b1[1]);
      pb[6] = (short)f2bf(b1[2]); pb[7] = (short)f2bf(b1[3]);
      *(short8*)((char*)Bl + off) = pb;
    }
    __syncthreads();
#pragma unroll
    for (int ks = 0; ks < 2; ++ks) {
      const int koffb = (ks * 32 + ((lane >> 4) << 3)) * 2;
      short8 af[4], bfr[4];
#pragma unroll
      for (int m = 0; m < 4; ++m) {
        const int row = wr + m * 16 + (lane & 15);
        af[m] = *(const short8*)((const char*)Al + ((row * 128 + koffb) ^ ((row & 7) << 4)));
      }
#pragma unroll
      for (int n = 0; n < 4; ++n) {
        const int row = wc + n * 16 + (lane & 15);
        bfr[n] = *(const short8*)((const char*)Bl + ((row * 128 + koffb) ^ ((row & 7) << 4)));
      }
#pragma unroll
      for (int m = 0; m < 4; ++m)
#pragma unroll
        for (int n = 0; n < 4; ++n)
          acc[m][n] = mfma_bf16(af[m], bfr[n], acc[m][n]);
    }
  }

#pragma unroll
  for (int n = 0; n < 4; ++n) {
    const int j = bn + wc + n * 16 + (lane & 15);
    const float bj = bias[j];
    const int h = j >> 6, d = j & 63;
#pragma unroll
    for (int m = 0; m < 4; ++m) {
      const int rbase = bm + wr + m * 16 + ((lane >> 4) << 2);
      const int b = rbase >> 12;
      const int s = rbase & (S_LEN - 1);
      if (!transposeOut) {
#pragma unroll
        for (int i = 0; i < 4; ++i) {
          const float v = (acc[m][n][i] + bj) * scale;
          out[(((size_t)(b * NHD + h) * S_LEN + (s + i)) << 6) + d] = f2bf(v);
        }
      } else {
        u16x4 pk;
#pragma unroll
        for (int i = 0; i < 4; ++i) pk[i] = f2bf((acc[m][n][i] + bj) * scale);
        *(u16x4*)(out + (((size_t)(b * NHD + h) * 64 + d) << 12) + s) = pk;
      }
    }
  }
}

// ---------------------------------------------------------------------------
// Fused attention — round-4 shape (4 waves / 256 thr / grid 512 / 2 blk/CU)
// with SINGLE-barrier double-buffered rounds:
//  - Kl[2] double buffer (32 KB): per round, ds_write tile kt+1 (from regs)
//    at round start, issue global loads for kt+2, compute on Kl[kt&1], then
//    ONE lgkm-only barrier. vmcnt never drained -> W-store stream continuous.
//  - V is NOT staged: PV B-fragments are coalesced 16-rows x 64-B direct
//    global reads, L2-resident (V/head = 512 KB, XCD swizzle). Loads issued
//    in two groups ahead of use so L2 latency hides under store-out/PV.
// Phases: A0 (denominators t0), P1 (B t0 + denominators t1 sharing the K
// fragments), P2 (B t1). B = recompute S, exp, normalize, fp32 W tile via
// per-wave LDS Wl transpose, 8x 1-KB nt stores (512-B contiguous segments),
// PV from Wl (bf16 convert in-register) x direct-global V.
// ---------------------------------------------------------------------------
__global__ __launch_bounds__(256, 2) void attn_kernel(
    const u16* __restrict__ Qp, const u16* __restrict__ Kp,
    const u16* __restrict__ Vt, const unsigned char* __restrict__ mask,
    float* __restrict__ outO, float* __restrict__ outW)
{
  __shared__ u16 Kl[2][128 * 64];     // K tile double buffer (32 KB)
  __shared__ float Wl[4][16 * 128];   // per-wave fp32 normalized P (32 KB)
  __shared__ u32 anyMaskSh;

  const int tid = threadIdx.x;
  const int lane = tid & 63;
  const int wid = tid >> 6;
  const int lr = lane & 15;
  const int lg = lane >> 4;

  // XCD-bijective swizzle: 512 blocks; each XCD gets a 64-block chunk = 2
  // heads (K+V+Q = 3 MB fits the 4 MB per-XCD L2).
  const int bid = blockIdx.x;
  const int swz = (bid & 7) * 64 + (bid >> 3);
  const int bh = swz >> 5;          // b*8 + h
  const int q0 = (swz & 31) << 7;   // 128 q-rows = tiles t0,t1
  const int b = bh >> 3;
  const int h = bh & 7;

  char* const Wlw = (char*)Wl[wid];

  // per-thread K staging offsets ([128][64] tile, 4 x 16-B chunks per thread)
  int koff[4], kgo[4];
#pragma unroll
  for (int i = 0; i < 4; ++i) {
    const int idx = i * 256 + tid;
    const int kr = idx >> 3, kc = idx & 7;
    koff[i] = (kr * 128 + kc * 16) ^ ((kr & 7) << 4);
    kgo[i] = (kr << 6) + kc * 8;
  }
  const u16* kgbase = Kp + ((size_t)bh << 18);

  if (tid == 0) anyMaskSh = 0u;
  __syncthreads();
  {
    u32x4 mv = *(const u32x4*)(mask + (size_t)b * S_LEN + tid * 16);
    if (mv[0] | mv[1] | mv[2] | mv[3]) atomicOr(&anyMaskSh, 1u);
  }
  __syncthreads();
  const bool anyMask = (anyMaskSh != 0u);

  // Q fragments (MFMA B operand) for both tiles, straight from global
  short8 bq[2][2];
#pragma unroll
  for (int t = 0; t < 2; ++t)
#pragma unroll
    for (int ks = 0; ks < 2; ++ks) {
      const int qr = q0 + (t << 6) + (wid << 4) + lr;
      bq[t][ks] = *(const short8*)(
          Qp + (((size_t)bh * S_LEN + qr) << 6) + ks * 32 + lg * 8);
    }

  const unsigned char* mrow = mask + (size_t)b * S_LEN + (lg << 2);
  u32x4 rK[4];

  // V fragment base: row (cd*16 + lr) of the head's V^T, col offset lg*8
#define VPTR(kt, kk, cd) ((const u32x4*)(Vt +                                  \
    (((size_t)((bh << 6) + ((cd) << 4) + lr)) << 12) +                         \
    ((kt) << 7) + ((kk) << 5) + (lg << 3)))

  // ---------------- phase A0: denominators for t0 ----------------
#pragma unroll
  for (int i = 0; i < 4; ++i) rK[i] = *(const u32x4*)(kgbase + kgo[i]);
#pragma unroll
  for (int i = 0; i < 4; ++i) *(u32x4*)((char*)Kl[0] + koff[i]) = rK[i];
#pragma unroll
  for (int i = 0; i < 4; ++i) rK[i] = *(const u32x4*)(kgbase + (1 << 13) + kgo[i]);
  WG_BARRIER();

  float lsum0 = 0.f;
#pragma unroll 1
  for (int kt = 0; kt < 32; ++kt) {
    const char* Kc = (const char*)Kl[kt & 1];
    if (kt < 31) {
#pragma unroll
      for (int i = 0; i < 4; ++i)
        *(u32x4*)((char*)Kl[(kt + 1) & 1] + koff[i]) = rK[i];
    }
    if (kt < 30) {
#pragma unroll
      for (int i = 0; i < 4; ++i)
        rK[i] = *(const u32x4*)(kgbase + ((size_t)(kt + 2) << 13) + kgo[i]);
    }
#pragma unroll
    for (int rb = 0; rb < 8; ++rb) {
      const int krow = (rb << 4) + lr;
      short8 ak0 = *(const short8*)(Kc +
          ((krow * 128 + (lg << 4)) ^ ((krow & 7) << 4)));
      short8 ak1 = *(const short8*)(Kc +
          ((krow * 128 + 64 + (lg << 4)) ^ ((krow & 7) << 4)));
      u32 mw = 0u;
      if (anyMask) mw = *(const u32*)(mrow + (kt << 7) + (rb << 4));
      f32x4 sv = {};
      sv = mfma_bf16(ak0, bq[0][0], sv);
      sv = mfma_bf16(ak1, bq[0][1], sv);
      float p0 = __expf(sv[0]);
      float p1 = __expf(sv[1]);
      float p2 = __expf(sv[2]);
      float p3 = __expf(sv[3]);
      if (mw) {
        if (mw & 0x000000FFu) p0 = 0.f;
        if (mw & 0x0000FF00u) p1 = 0.f;
        if (mw & 0x00FF0000u) p2 = 0.f;
        if (mw & 0xFF000000u) p3 = 0.f;
      }
      lsum0 += (p0 + p1) + (p2 + p3);
    }
    WG_BARRIER();
  }
  float inv0;
  {
    float t = lsum0;
    t += __shfl_xor(t, 16);
    t += __shfl_xor(t, 32);
    inv0 = 1.0f / t;
  }

  // ---------------- phase 1: B(t0) + A(t1) ----------------
#pragma unroll
  for (int i = 0; i < 4; ++i) rK[i] = *(const u32x4*)(kgbase + kgo[i]);
#pragma unroll
  for (int i = 0; i < 4; ++i) *(u32x4*)((char*)Kl[0] + koff[i]) = rK[i];
#pragma unroll
  for (int i = 0; i < 4; ++i) rK[i] = *(const u32x4*)(kgbase + (1 << 13) + kgo[i]);
  WG_BARRIER();

  float lsum1 = 0.f;
  f32x4 oacc[4] = {};
  float* const wb0 = outW + ((size_t)(bh * S_LEN + q0 + (wid << 4)) << 12);
#pragma unroll 1
  for (int kt = 0; kt < 32; ++kt) {
    const char* Kc = (const char*)Kl[kt & 1];
    if (kt < 31) {
#pragma unroll
      for (int i = 0; i < 4; ++i)
        *(u32x4*)((char*)Kl[(kt + 1) & 1] + koff[i]) = rK[i];
    }
    if (kt < 30) {
#pragma unroll
      for (int i = 0; i < 4; ++i)
        rK[i] = *(const u32x4*)(kgbase + ((size_t)(kt + 2) << 13) + kgo[i]);
    }
#pragma unroll
    for (int rb = 0; rb < 8; ++rb) {
      const int krow = (rb << 4) + lr;
      short8 ak0 = *(const short8*)(Kc +
          ((krow * 128 + (lg << 4)) ^ ((krow & 7) << 4)));
      short8 ak1 = *(const short8*)(Kc +
          ((krow * 128 + 64 + (lg << 4)) ^ ((krow & 7) << 4)));
      u32 mw = 0u;
      if (anyMask) mw = *(const u32*)(mrow + (kt << 7) + (rb << 4));
      // B for t0: normalized fp32 P -> Wl (swizzled)
      {
        f32x4 sv = {};
        sv = mfma_bf16(ak0, bq[0][0], sv);
        sv = mfma_bf16(ak1, bq[0][1], sv);
        float p0 = __expf(sv[0]) * inv0;
        float p1 = __expf(sv[1]) * inv0;
        float p2 = __expf(sv[2]) * inv0;
        float p3 = __expf(sv[3]) * inv0;
        if (mw) {
          if (mw & 0x000000FFu) p0 = 0.f;
          if (mw & 0x0000FF00u) p1 = 0.f;
          if (mw & 0x00FF0000u) p2 = 0.f;
          if (mw & 0xFF000000u) p3 = 0.f;
        }
        f32x4 wv; wv[0] = p0; wv[1] = p1; wv[2] = p2; wv[3] = p3;
        *(f32x4*)(Wlw + (((lr << 9) + (rb << 6) + (lg << 4)) ^ ((lr & 7) << 4))) = wv;
      }
      // A for t1 (same ak fragments — K rows are q-independent)
      {
        f32x4 sv = {};
        sv = mfma_bf16(ak0, bq[1][0], sv);
        sv = mfma_bf16(ak1, bq[1][1], sv);
        float p0 = __expf(sv[0]);
        float p1 = __expf(sv[1]);
        float p2 = __expf(sv[2]);
        float p3 = __expf(sv[3]);
        if (mw) {
          if (mw & 0x000000FFu) p0 = 0.f;
          if (mw & 0x0000FF00u) p1 = 0.f;
          if (mw & 0x00FF0000u) p2 = 0.f;
          if (mw & 0xFF000000u) p3 = 0.f;
        }
        lsum1 += (p0 + p1) + (p2 + p3);
      }
    }
    // V fragments kk=0,1 issued here: latency hides under store-out
    u32x4 v0[4], v1[4], v2[4], v3[4];
#pragma unroll
    for (int cd = 0; cd < 4; ++cd) v0[cd] = *VPTR(kt, 0, cd);
#pragma unroll
    for (int cd = 0; cd < 4; ++cd) v1[cd] = *VPTR(kt, 1, cd);
    // store-out: read Wl row-major, 8x 1-KB nt stores (2x contiguous 512 B)
#pragma unroll
    for (int i = 0; i < 8; ++i) {
      const int row = (i << 1) + (lane >> 5);
      f32x4 wv = *(const f32x4*)(Wlw +
          (((row << 9) + ((lane & 31) << 4)) ^ ((row & 7) << 4)));
      __builtin_nontemporal_store(wv,
          (f32x4*)(wb0 + ((size_t)row << 12) + (kt << 7) + ((lane & 31) << 2)));
    }
#pragma unroll
    for (int cd = 0; cd < 4; ++cd) v2[cd] = *VPTR(kt, 2, cd);
#pragma unroll
    for (int cd = 0; cd < 4; ++cd) v3[cd] = *VPTR(kt, 3, cd);
    // PV for t0: read fp32 P from Wl (same-wave RAW), convert to bf16
#pragma unroll
    for (int kk = 0; kk < 4; ++kk) {
      const int wbo = (lr << 9) + (kk << 7) + (lg << 5);
      f32x4 a0 = *(const f32x4*)(Wlw + (wbo ^ ((lr & 7) << 4)));
      f32x4 a1 = *(const f32x4*)(Wlw + ((wbo + 16) ^ ((lr & 7) << 4)));
      short8 ap;
      ap[0] = (short)f2bf(a0[0]); ap[1] = (short)f2bf(a0[1]);
      ap[2] = (short)f2bf(a0[2]); ap[3] = (short)f2bf(a0[3]);
      ap[4] = (short)f2bf(a1[0]); ap[5] = (short)f2bf(a1[1]);
      ap[6] = (short)f2bf(a1[2]); ap[7] = (short)f2bf(a1[3]);
      const u32x4* vg = (kk == 0) ? v0 : (kk == 1) ? v1 : (kk == 2) ? v2 : v3;
#pragma unroll
      for (int cd = 0; cd < 4; ++cd)
        oacc[cd] = mfma_bf16(ap, __builtin_bit_cast(short8, vg[cd]), oacc[cd]);
    }
    WG_BARRIER();
  }
  float inv1;
  {
    float t = lsum1;
    t += __shfl_xor(t, 16);
    t += __shfl_xor(t, 32);
    inv1 = 1.0f / t;
  }
  // write O(t0); free oacc for t1
#pragma unroll
  for (int cd = 0; cd < 4; ++cd)
#pragma unroll
    for (int i = 0; i < 4; ++i) {
      const int q = q0 + (wid << 4) + (lg << 2) + i;
      const int d = (cd << 4) + lr;
      __builtin_nontemporal_store(oacc[cd][i],
          outO + (((size_t)b * S_LEN + q) << 9) + h * 64 + d);
      oacc[cd][i] = 0.f;
    }

  // ---------------- phase 2: B(t1) ----------------
#pragma unroll
  for (int i = 0; i < 4; ++i) rK[i] = *(const u32x4*)(kgbase + kgo[i]);
#pragma unroll
  for (int i = 0; i < 4; ++i) *(u32x4*)((char*)Kl[0] + koff[i]) = rK[i];
#pragma unroll
  for (int i = 0; i < 4; ++i) rK[i] = *(const u32x4*)(kgbase + (1 << 13) + kgo[i]);
  WG_BARRIER();

  float* const wb1 = outW + ((size_t)(bh * S_LEN + q0 + 64 + (wid << 4)) << 12);
#pragma unroll 1
  for (int kt = 0; kt < 32; ++kt) {
    const char* Kc = (const char*)Kl[kt & 1];
    if (kt < 31) {
#pragma unroll
      for (int i = 0; i < 4; ++i)
        *(u32x4*)((char*)Kl[(kt + 1) & 1] + koff[i]) = rK[i];
    }
    if (kt < 30) {
#pragma unroll
      for (int i = 0; i < 4; ++i)
        rK[i] = *(const u32x4*)(kgbase + ((size_t)(kt + 2) << 13) + kgo[i]);
    }
#pragma unroll
    for (int rb = 0; rb < 8; ++rb) {
      const int krow = (rb << 4) + lr;
      short8 ak0 = *(const short8*)(Kc +
          ((krow * 128 + (lg << 4)) ^ ((krow & 7) << 4)));
      short8 ak1 = *(const short8*)(Kc +
          ((krow * 128 + 64 + (lg << 4)) ^ ((krow & 7) << 4)));
      u32 mw = 0u;
      if (anyMask) mw = *(const u32*)(mrow + (kt << 7) + (rb << 4));
      f32x4 sv = {};
      sv = mfma_bf16(ak0, bq[1][0], sv);
      sv = mfma_bf16(ak1, bq[1][1], sv);
      float p0 = __expf(sv[0]) * inv1;
      float p1 = __expf(sv[1]) * inv1;
      float p2 = __expf(sv[2]) * inv1;
      float p3 = __expf(sv[3]) * inv1;
      if (mw) {
        if (mw & 0x000000FFu) p0 = 0.f;
        if (mw & 0x0000FF00u) p1 = 0.f;
        if (mw & 0x00FF0000u) p2 = 0.f;
        if (mw & 0xFF000000u) p3 = 0.f;
      }
      f32x4 wv; wv[0] = p0; wv[1] = p1; wv[2] = p2; wv[3] = p3;
      *(f32x4*)(Wlw + (((lr << 9) + (rb << 6) + (lg << 4)) ^ ((lr & 7) << 4))) = wv;
    }
    u32x4 v0[4], v1[4], v2[4], v3[4];
#pragma unroll
    for (int cd = 0; cd < 4; ++cd) v0[cd] = *VPTR(kt, 0, cd);
#pragma unroll
    for (int cd = 0; cd < 4; ++cd) v1[cd] = *VPTR(kt, 1, cd);
#pragma unroll
    for (int i = 0; i < 8; ++i) {
      const int row = (i << 1) + (lane >> 5);
      f32x4 wv = *(const f32x4*)(Wlw +
          (((row << 9) + ((lane & 31) << 4)) ^ ((row & 7) << 4)));
      __builtin_nontemporal_store(wv,
          (f32x4*)(wb1 + ((size_t)row << 12) + (kt << 7) + ((lane & 31) << 2)));
    }
#pragma unroll
    for (int cd = 0; cd < 4; ++cd) v2[cd] = *VPTR(kt, 2, cd);
#pragma unroll
    for (int cd = 0; cd < 4; ++cd) v3[cd] = *VPTR(kt, 3, cd);
#pragma unroll
    for (int kk = 0; kk < 4; ++kk) {
      const int wbo = (lr << 9) + (kk << 7) + (lg << 5);
      f32x4 a0 = *(const f32x4*)(Wlw + (wbo ^ ((lr & 7) << 4)));
      f32x4 a1 = *(const f32x4*)(Wlw + ((wbo + 16) ^ ((lr & 7) << 4)));
      short8 ap;
      ap[0] = (short)f2bf(a0[0]); ap[1] = (short)f2bf(a0[1]);
      ap[2] = (short)f2bf(a0[2]); ap[3] = (short)f2bf(a0[3]);
      ap[4] = (short)f2bf(a1[0]); ap[5] = (short)f2bf(a1[1]);
      ap[6] = (short)f2bf(a1[2]); ap[7] = (short)f2bf(a1[3]);
      const u32x4* vg = (kk == 0) ? v0 : (kk == 1) ? v1 : (kk == 2) ? v2 : v3;
#pragma unroll
      for (int cd = 0; cd < 4; ++cd)
        oacc[cd] = mfma_bf16(ap, __builtin_bit_cast(short8, vg[cd]), oacc[cd]);
    }
    WG_BARRIER();
  }
  // write O(t1)
#pragma unroll
  for (int cd = 0; cd < 4; ++cd)
#pragma unroll
    for (int i = 0; i < 4; ++i) {
      const int q = q0 + 64 + (wid << 4) + (lg << 2) + i;
      const int d = (cd << 4) + lr;
      __builtin_nontemporal_store(oacc[cd][i],
          outO + (((size_t)b * S_LEN + q) << 9) + h * 64 + d);
    }
#undef VPTR
}

extern "C" void kernel_launch(void* const* d_in, const int* in_sizes, int n_in,
                              void* d_out, int out_size, void* d_ws, size_t ws_size,
                              hipStream_t stream) {
  (void)in_sizes; (void)n_in; (void)out_size; (void)ws_size;
  const float* query = (const float*)d_in[0];
  const float* key_i = (const float*)d_in[1];
  const float* value = (const float*)d_in[2];
  const unsigned char* kpm = (const unsigned char*)d_in[3];
  const float* Wq = (const float*)d_in[4];
  const float* bq_ = (const float*)d_in[5];
  const float* Wk = (const float*)d_in[6];
  const float* bk_ = (const float*)d_in[7];
  const float* Wv = (const float*)d_in[8];
  const float* bv_ = (const float*)d_in[9];

  u16* Qp = (u16*)d_ws;                                  // [16][4096][64] bf16
  u16* Kp = Qp + (size_t)NB * NHD * S_LEN * 64;          // [16][4096][64] bf16
  u16* Vt = Kp + (size_t)NB * NHD * S_LEN * 64;          // [16][64][4096] bf16

  float* outO = (float*)d_out;
  float* outW = outO + (size_t)NB * S_LEN * HID;

  // fused Q/K/V projections: one launch, 768 blocks (3 blocks/CU)
  proj_kernel<<<dim3(64, 4, 3), dim3(256), 0, stream>>>(
      query, key_i, value, Wq, Wk, Wv, bq_, bk_, bv_, Qp, Kp, Vt);
  attn_kernel<<<dim3(512), dim3(256), 0, stream>>>(Qp, Kp, Vt, kpm, outO, outW);
}

// Round 8
// 315.728 us; speedup vs baseline: 1.2797x; 1.2797x over previous
//
#include <hip/hip_runtime.h>

typedef __attribute__((ext_vector_type(4))) float f32x4;
typedef __attribute__((ext_vector_type(8))) short short8;
typedef __attribute__((ext_vector_type(8))) __bf16 bf16x8;
typedef __attribute__((ext_vector_type(4))) unsigned int u32x4;
typedef __attribute__((ext_vector_type(4))) unsigned short u16x4;
typedef unsigned short u16;
typedef unsigned int u32;

#define NB 2
#define S_LEN 4096
#define NHD 8
#define HID 512

__device__ __forceinline__ u16 f2bf(float f) {
  u32 u = __builtin_bit_cast(u32, f);
  u += 0x7fffu + ((u >> 16) & 1u);   // round-to-nearest-even
  return (u16)(u >> 16);
}

// MFMA wrapper hedged over the two plausible builtin signatures (V8s vs V8y).
template <typename V>
static __device__ __forceinline__ auto mfma_imp(V a, V b, f32x4 c, int)
    -> decltype(__builtin_amdgcn_mfma_f32_16x16x32_bf16(a, b, c, 0, 0, 0)) {
  return __builtin_amdgcn_mfma_f32_16x16x32_bf16(a, b, c, 0, 0, 0);
}
template <typename V>
static __device__ __forceinline__ f32x4 mfma_imp(V a, V b, f32x4 c, long) {
  return __builtin_amdgcn_mfma_f32_16x16x32_bf16(
      __builtin_bit_cast(bf16x8, a), __builtin_bit_cast(bf16x8, b), c, 0, 0, 0);
}
static __device__ __forceinline__ f32x4 mfma_bf16(short8 a, short8 b, f32x4 c) {
  return mfma_imp(a, b, c, 0);
}

// Raw workgroup barrier that does NOT drain vmcnt: own LDS ops flushed
// (lgkmcnt 0), scheduler pinned (rule 18), then s_barrier. Global loads and
// the nontemporal W-store stream stay in flight across it.
#define WG_BARRIER()                                        \
  do {                                                      \
    asm volatile("s_waitcnt lgkmcnt(0)" ::: "memory");      \
    __builtin_amdgcn_sched_barrier(0);                      \
    __builtin_amdgcn_s_barrier();                           \
    __builtin_amdgcn_sched_barrier(0);                      \
  } while (0)

// ---------------------------------------------------------------------------
// Fused projection GEMM (Q, K, V in one launch via blockIdx.z):
// C[i][j] = sum_k X[i][k] * W[j][k] + bias[j], scaled, ->bf16
// z==0 (Q): out [(b*8+h)][s][64], scale 0.125 (1/sqrt(64) folded in)
// z==1 (K): out [(b*8+h)][s][64]
// z==2 (V): out [(b*8+h)][64][s]  (V^T so PV B-operand is contiguous)
// ---------------------------------------------------------------------------
__global__ __launch_bounds__(256, 2) void proj_kernel(
    const float* __restrict__ Xq, const float* __restrict__ Xk,
    const float* __restrict__ Xv, const float* __restrict__ Wq,
    const float* __restrict__ Wk, const float* __restrict__ Wv,
    const float* __restrict__ bq_, const float* __restrict__ bk_,
    const float* __restrict__ bv_, u16* __restrict__ oq,
    u16* __restrict__ ok, u16* __restrict__ ov)
{
  __shared__ u16 Al[128 * 64];
  __shared__ u16 Bl[128 * 64];
  const int z = blockIdx.z;
  const float* X = (z == 0) ? Xq : (z == 1) ? Xk : Xv;
  const float* W = (z == 0) ? Wq : (z == 1) ? Wk : Wv;
  const float* bias = (z == 0) ? bq_ : (z == 1) ? bk_ : bv_;
  u16* out = (z == 0) ? oq : (z == 1) ? ok : ov;
  const int transposeOut = (z == 2);
  const float scale = (z == 0) ? 0.125f : 1.0f;

  const int tid = threadIdx.x;
  const int lane = tid & 63;
  const int wid = tid >> 6;
  const int wr = (wid >> 1) << 6;
  const int wc = (wid & 1) << 6;
  const int bm = blockIdx.x << 7;
  const int bn = blockIdx.y << 7;

  f32x4 acc[4][4] = {};

#pragma unroll 1
  for (int k0 = 0; k0 < HID; k0 += 64) {
    __syncthreads();
#pragma unroll
    for (int i = 0; i < 4; ++i) {
      const int idx = i * 256 + tid;
      const int row = idx >> 3;     // 8 chunks of 8 elems per 64-wide row
      const int c = idx & 7;
      const int off = (row * 128 + c * 16) ^ ((row & 7) << 4);
      const float* ga = X + (size_t)(bm + row) * HID + k0 + c * 8;
      f32x4 a0 = *(const f32x4*)ga;
      f32x4 a1 = *(const f32x4*)(ga + 4);
      short8 pa;
      pa[0] = (short)f2bf(a0[0]); pa[1] = (short)f2bf(a0[1]);
      pa[2] = (short)f2bf(a0[2]); pa[3] = (short)f2bf(a0[3]);
      pa[4] = (short)f2bf(a1[0]); pa[5] = (short)f2bf(a1[1]);
      pa[6] = (short)f2bf(a1[2]); pa[7] = (short)f2bf(a1[3]);
      *(short8*)((char*)Al + off) = pa;
      const float* gb = W + (size_t)(bn + row) * HID + k0 + c * 8;
      f32x4 b0 = *(const f32x4*)gb;
      f32x4 b1 = *(const f32x4*)(gb + 4);
      short8 pb;
      pb[0] = (short)f2bf(b0[0]); pb[1] = (short)f2bf(b0[1]);
      pb[2] = (short)f2bf(b0[2]); pb[3] = (short)f2bf(b0[3]);
      pb[4] = (short)f2bf(b1[0]); pb[5] = (short)f2bf(b1[1]);
      pb[6] = (short)f2bf(b1[2]); pb[7] = (short)f2bf(b1[3]);
      *(short8*)((char*)Bl + off) = pb;
    }
    __syncthreads();
#pragma unroll
    for (int ks = 0; ks < 2; ++ks) {
      const int koffb = (ks * 32 + ((lane >> 4) << 3)) * 2;
      short8 af[4], bfr[4];
#pragma unroll
      for (int m = 0; m < 4; ++m) {
        const int row = wr + m * 16 + (lane & 15);
        af[m] = *(const short8*)((const char*)Al + ((row * 128 + koffb) ^ ((row & 7) << 4)));
      }
#pragma unroll
      for (int n = 0; n < 4; ++n) {
        const int row = wc + n * 16 + (lane & 15);
        bfr[n] = *(const short8*)((const char*)Bl + ((row * 128 + koffb) ^ ((row & 7) << 4)));
      }
#pragma unroll
      for (int m = 0; m < 4; ++m)
#pragma unroll
        for (int n = 0; n < 4; ++n)
          acc[m][n] = mfma_bf16(af[m], bfr[n], acc[m][n]);
    }
  }

#pragma unroll
  for (int n = 0; n < 4; ++n) {
    const int j = bn + wc + n * 16 + (lane & 15);
    const float bj = bias[j];
    const int h = j >> 6, d = j & 63;
#pragma unroll
    for (int m = 0; m < 4; ++m) {
      const int rbase = bm + wr + m * 16 + ((lane >> 4) << 2);
      const int b = rbase >> 12;
      const int s = rbase & (S_LEN - 1);
      if (!transposeOut) {
#pragma unroll
        for (int i = 0; i < 4; ++i) {
          const float v = (acc[m][n][i] + bj) * scale;
          out[(((size_t)(b * NHD + h) * S_LEN + (s + i)) << 6) + d] = f2bf(v);
        }
      } else {
        u16x4 pk;
#pragma unroll
        for (int i = 0; i < 4; ++i) pk[i] = f2bf((acc[m][n][i] + bj) * scale);
        *(u16x4*)(out + (((size_t)(b * NHD + h) * 64 + d) << 12) + s) = pk;
      }
    }
  }
}

// ---------------------------------------------------------------------------
// Fused attention — round-4 structure (verified 307.5 us) + single-barrier A0.
// One WG per (b*8+h, 128 q-rows) = two 64-row tiles t0,t1; 4 waves x 16
// q-rows per tile; grid 512 = 2 blocks/CU (proven necessary: round-5's
// 1 blk/CU regressed). K and V staged in LDS (proven necessary: round-6's
// direct-global V regressed).
// Phases: A0 (denominators t0), P1 (B t0 + denominators t1 sharing K
// fragments), P2 (B t1) — pipelined staging with non-draining barriers.
// A0 only: single-barrier double-buffered K rounds, alternating Kl/Vl as the
// K buffer (Vl is idle in A0) — A0 has no store stream to cover barrier
// skew, so halving its barrier count is free.
// B = recompute S, exp, normalize, fp32 W tile via per-wave LDS Wl
// transpose, 8x 1-KB nt stores (512-B contiguous row segments), PV from Wl
// (bf16 convert in-register) x staged Vl.
// ---------------------------------------------------------------------------
__global__ __launch_bounds__(256, 2) void attn_kernel(
    const u16* __restrict__ Qp, const u16* __restrict__ Kp,
    const u16* __restrict__ Vt, const unsigned char* __restrict__ mask,
    float* __restrict__ outO, float* __restrict__ outW)
{
  __shared__ u16 Kl[128 * 64];        // K tile (16 KB)
  __shared__ u16 Vl[64 * 128];        // V^T tile (16 KB); K alt-buffer in A0
  __shared__ float Wl[4][16 * 128];   // per-wave fp32 normalized P (32 KB)
  __shared__ u32 anyMaskSh;

  const int tid = threadIdx.x;
  const int lane = tid & 63;
  const int wid = tid >> 6;
  const int lr = lane & 15;
  const int lg = lane >> 4;

  // XCD-bijective swizzle: 512 blocks; each XCD gets a 64-block chunk = 2
  // heads (K+V+Q = 3 MB fits the 4 MB per-XCD L2).
  const int bid = blockIdx.x;
  const int swz = (bid & 7) * 64 + (bid >> 3);
  const int bh = swz >> 5;          // b*8 + h
  const int q0 = (swz & 31) << 7;   // 128 q-rows = tiles t0,t1
  const int b = bh >> 3;
  const int h = bh & 7;

  char* const Wlw = (char*)Wl[wid];

  // per-thread staging offsets (K tile: [128][64]; V tile: [64][128] keys)
  int koff[4], kgo[4], voff[4], vgo[4];
#pragma unroll
  for (int i = 0; i < 4; ++i) {
    const int idx = i * 256 + tid;
    const int kr = idx >> 3, kc = idx & 7;
    koff[i] = (kr * 128 + kc * 16) ^ ((kr & 7) << 4);
    kgo[i] = (kr << 6) + kc * 8;
    const int vr = idx >> 4, vc = idx & 15;
    voff[i] = (vr * 256 + vc * 16) ^ ((vr & 7) << 4);
    vgo[i] = (vr << 12) + vc * 8;
  }
  const u16* kgbase = Kp + ((size_t)bh << 18);
  const u16* vgbase = Vt + ((size_t)bh << 18);

  if (tid == 0) anyMaskSh = 0u;
  __syncthreads();
  {
    u32x4 mv = *(const u32x4*)(mask + (size_t)b * S_LEN + tid * 16);
    if (mv[0] | mv[1] | mv[2] | mv[3]) atomicOr(&anyMaskSh, 1u);
  }
  __syncthreads();
  const bool anyMask = (anyMaskSh != 0u);

  // Q fragments (MFMA B operand) for both tiles, straight from global
  short8 bq[2][2];
#pragma unroll
  for (int t = 0; t < 2; ++t)
#pragma unroll
    for (int ks = 0; ks < 2; ++ks) {
      const int qr = q0 + (t << 6) + (wid << 4) + lr;
      bq[t][ks] = *(const short8*)(
          Qp + (((size_t)bh * S_LEN + qr) << 6) + ks * 32 + lg * 8);
    }

  const unsigned char* mrow = mask + (size_t)b * S_LEN + (lg << 2);
  u32x4 rK[4], rV[4];

  // ---------------- phase A0: denominators for t0 ----------------
  // single-barrier double-buffered K rounds: Kl and Vl alternate as the K
  // tile buffer (Vl is otherwise idle in A0).
  char* const kb0 = (char*)Kl;
  char* const kb1 = (char*)Vl;
#pragma unroll
  for (int i = 0; i < 4; ++i) rK[i] = *(const u32x4*)(kgbase + kgo[i]);
#pragma unroll
  for (int i = 0; i < 4; ++i) *(u32x4*)(kb0 + koff[i]) = rK[i];
#pragma unroll
  for (int i = 0; i < 4; ++i) rK[i] = *(const u32x4*)(kgbase + (1 << 13) + kgo[i]);
  WG_BARRIER();

  float lsum0 = 0.f;
#pragma unroll 1
  for (int kt = 0; kt < 32; ++kt) {
    const char* Kc = (kt & 1) ? kb1 : kb0;
    char* const Kn = (kt & 1) ? kb0 : kb1;
    if (kt < 31) {
#pragma unroll
      for (int i = 0; i < 4; ++i) *(u32x4*)(Kn + koff[i]) = rK[i];
    }
    if (kt < 30) {
#pragma unroll
      for (int i = 0; i < 4; ++i)
        rK[i] = *(const u32x4*)(kgbase + ((size_t)(kt + 2) << 13) + kgo[i]);
    }
#pragma unroll
    for (int rb = 0; rb < 8; ++rb) {
      const int krow = (rb << 4) + lr;
      short8 ak0 = *(const short8*)(Kc +
          ((krow * 128 + (lg << 4)) ^ ((krow & 7) << 4)));
      short8 ak1 = *(const short8*)(Kc +
          ((krow * 128 + 64 + (lg << 4)) ^ ((krow & 7) << 4)));
      u32 mw = 0u;
      if (anyMask) mw = *(const u32*)(mrow + (kt << 7) + (rb << 4));
      f32x4 sv = {};
      sv = mfma_bf16(ak0, bq[0][0], sv);
      sv = mfma_bf16(ak1, bq[0][1], sv);
      float p0 = __expf(sv[0]);
      float p1 = __expf(sv[1]);
      float p2 = __expf(sv[2]);
      float p3 = __expf(sv[3]);
      if (mw) {
        if (mw & 0x000000FFu) p0 = 0.f;
        if (mw & 0x0000FF00u) p1 = 0.f;
        if (mw & 0x00FF0000u) p2 = 0.f;
        if (mw & 0xFF000000u) p3 = 0.f;
      }
      lsum0 += (p0 + p1) + (p2 + p3);
    }
    WG_BARRIER();
  }
  float inv0;
  {
    float t = lsum0;
    t += __shfl_xor(t, 16);
    t += __shfl_xor(t, 32);
    inv0 = 1.0f / t;
  }

  // ---------------- phase 1: B(t0) + A(t1) ----------------
#pragma unroll
  for (int i = 0; i < 4; ++i) {
    rK[i] = *(const u32x4*)(kgbase + kgo[i]);
    rV[i] = *(const u32x4*)(vgbase + vgo[i]);
  }
#pragma unroll
  for (int i = 0; i < 4; ++i) {
    *(u32x4*)((char*)Kl + koff[i]) = rK[i];
    *(u32x4*)((char*)Vl + voff[i]) = rV[i];
  }
#pragma unroll
  for (int i = 0; i < 4; ++i) {
    rK[i] = *(const u32x4*)(kgbase + (1 << 13) + kgo[i]);
    rV[i] = *(const u32x4*)(vgbase + (1 << 7) + vgo[i]);
  }
  WG_BARRIER();

  float lsum1 = 0.f;
  f32x4 oacc[4] = {};
  float* const wb0 = outW + ((size_t)(bh * S_LEN + q0 + (wid << 4)) << 12);
#pragma unroll 1
  for (int kt = 0; kt < 32; ++kt) {
#pragma unroll
    for (int rb = 0; rb < 8; ++rb) {
      const int krow = (rb << 4) + lr;
      short8 ak0 = *(const short8*)((const char*)Kl +
          ((krow * 128 + (lg << 4)) ^ ((krow & 7) << 4)));
      short8 ak1 = *(const short8*)((const char*)Kl +
          ((krow * 128 + 64 + (lg << 4)) ^ ((krow & 7) << 4)));
      u32 mw = 0u;
      if (anyMask) mw = *(const u32*)(mrow + (kt << 7) + (rb << 4));
      // B for t0: normalized fp32 P -> Wl (swizzled)
      {
        f32x4 sv = {};
        sv = mfma_bf16(ak0, bq[0][0], sv);
        sv = mfma_bf16(ak1, bq[0][1], sv);
        float p0 = __expf(sv[0]) * inv0;
        float p1 = __expf(sv[1]) * inv0;
        float p2 = __expf(sv[2]) * inv0;
        float p3 = __expf(sv[3]) * inv0;
        if (mw) {
          if (mw & 0x000000FFu) p0 = 0.f;
          if (mw & 0x0000FF00u) p1 = 0.f;
          if (mw & 0x00FF0000u) p2 = 0.f;
          if (mw & 0xFF000000u) p3 = 0.f;
        }
        f32x4 wv; wv[0] = p0; wv[1] = p1; wv[2] = p2; wv[3] = p3;
        *(f32x4*)(Wlw + (((lr << 9) + (rb << 6) + (lg << 4)) ^ ((lr & 7) << 4))) = wv;
      }
      // A for t1 (same ak fragments — K rows are q-independent)
      {
        f32x4 sv = {};
        sv = mfma_bf16(ak0, bq[1][0], sv);
        sv = mfma_bf16(ak1, bq[1][1], sv);
        float p0 = __expf(sv[0]);
        float p1 = __expf(sv[1]);
        float p2 = __expf(sv[2]);
        float p3 = __expf(sv[3]);
        if (mw) {
          if (mw & 0x000000FFu) p0 = 0.f;
          if (mw & 0x0000FF00u) p1 = 0.f;
          if (mw & 0x00FF0000u) p2 = 0.f;
          if (mw & 0xFF000000u) p3 = 0.f;
        }
        lsum1 += (p0 + p1) + (p2 + p3);
      }
    }
    // store-out: read Wl row-major, 8x 1-KB nt stores (2x contiguous 512 B)
#pragma unroll
    for (int i = 0; i < 8; ++i) {
      const int row = (i << 1) + (lane >> 5);
      f32x4 wv = *(const f32x4*)(Wlw +
          (((row << 9) + ((lane & 31) << 4)) ^ ((row & 7) << 4)));
      __builtin_nontemporal_store(wv,
          (f32x4*)(wb0 + ((size_t)row << 12) + (kt << 7) + ((lane & 31) << 2)));
    }
    // PV for t0: read fp32 P from Wl (same-wave RAW), convert to bf16
#pragma unroll
    for (int kk = 0; kk < 4; ++kk) {
      const int wbo = (lr << 9) + (kk << 7) + (lg << 5);
      f32x4 a0 = *(const f32x4*)(Wlw + (wbo ^ ((lr & 7) << 4)));
      f32x4 a1 = *(const f32x4*)(Wlw + ((wbo + 16) ^ ((lr & 7) << 4)));
      short8 ap;
      ap[0] = (short)f2bf(a0[0]); ap[1] = (short)f2bf(a0[1]);
      ap[2] = (short)f2bf(a0[2]); ap[3] = (short)f2bf(a0[3]);
      ap[4] = (short)f2bf(a1[0]); ap[5] = (short)f2bf(a1[1]);
      ap[6] = (short)f2bf(a1[2]); ap[7] = (short)f2bf(a1[3]);
#pragma unroll
      for (int cd = 0; cd < 4; ++cd) {
        const int drow = (cd << 4) + lr;
        short8 bv = *(const short8*)((const char*)Vl +
            ((drow * 256 + (kk << 6) + (lg << 4)) ^ ((drow & 7) << 4)));
        oacc[cd] = mfma_bf16(ap, bv, oacc[cd]);
      }
    }
    WG_BARRIER();
    if (kt < 31) {
#pragma unroll
      for (int i = 0; i < 4; ++i) {
        *(u32x4*)((char*)Kl + koff[i]) = rK[i];
        *(u32x4*)((char*)Vl + voff[i]) = rV[i];
      }
    }
    if (kt < 30) {
#pragma unroll
      for (int i = 0; i < 4; ++i) {
        rK[i] = *(const u32x4*)(kgbase + ((size_t)(kt + 2) << 13) + kgo[i]);
        rV[i] = *(const u32x4*)(vgbase + ((size_t)(kt + 2) << 7) + vgo[i]);
      }
    }
    WG_BARRIER();
  }
  float inv1;
  {
    float t = lsum1;
    t += __shfl_xor(t, 16);
    t += __shfl_xor(t, 32);
    inv1 = 1.0f / t;
  }
  // write O(t0); free oacc for t1
#pragma unroll
  for (int cd = 0; cd < 4; ++cd)
#pragma unroll
    for (int i = 0; i < 4; ++i) {
      const int q = q0 + (wid << 4) + (lg << 2) + i;
      const int d = (cd << 4) + lr;
      __builtin_nontemporal_store(oacc[cd][i],
          outO + (((size_t)b * S_LEN + q) << 9) + h * 64 + d);
      oacc[cd][i] = 0.f;
    }

  // ---------------- phase 2: B(t1) ----------------
#pragma unroll
  for (int i = 0; i < 4; ++i) {
    rK[i] = *(const u32x4*)(kgbase + kgo[i]);
    rV[i] = *(const u32x4*)(vgbase + vgo[i]);
  }
#pragma unroll
  for (int i = 0; i < 4; ++i) {
    *(u32x4*)((char*)Kl + koff[i]) = rK[i];
    *(u32x4*)((char*)Vl + voff[i]) = rV[i];
  }
#pragma unroll
  for (int i = 0; i < 4; ++i) {
    rK[i] = *(const u32x4*)(kgbase + (1 << 13) + kgo[i]);
    rV[i] = *(const u32x4*)(vgbase + (1 << 7) + vgo[i]);
  }
  WG_BARRIER();

  float* const wb1 = outW + ((size_t)(bh * S_LEN + q0 + 64 + (wid << 4)) << 12);
#pragma unroll 1
  for (int kt = 0; kt < 32; ++kt) {
#pragma unroll
    for (int rb = 0; rb < 8; ++rb) {
      const int krow = (rb << 4) + lr;
      short8 ak0 = *(const short8*)((const char*)Kl +
          ((krow * 128 + (lg << 4)) ^ ((krow & 7) << 4)));
      short8 ak1 = *(const short8*)((const char*)Kl +
          ((krow * 128 + 64 + (lg << 4)) ^ ((krow & 7) << 4)));
      u32 mw = 0u;
      if (anyMask) mw = *(const u32*)(mrow + (kt << 7) + (rb << 4));
      f32x4 sv = {};
      sv = mfma_bf16(ak0, bq[1][0], sv);
      sv = mfma_bf16(ak1, bq[1][1], sv);
      float p0 = __expf(sv[0]) * inv1;
      float p1 = __expf(sv[1]) * inv1;
      float p2 = __expf(sv[2]) * inv1;
      float p3 = __expf(sv[3]) * inv1;
      if (mw) {
        if (mw & 0x000000FFu) p0 = 0.f;
        if (mw & 0x0000FF00u) p1 = 0.f;
        if (mw & 0x00FF0000u) p2 = 0.f;
        if (mw & 0xFF000000u) p3 = 0.f;
      }
      f32x4 wv; wv[0] = p0; wv[1] = p1; wv[2] = p2; wv[3] = p3;
      *(f32x4*)(Wlw + (((lr << 9) + (rb << 6) + (lg << 4)) ^ ((lr & 7) << 4))) = wv;
    }
#pragma unroll
    for (int i = 0; i < 8; ++i) {
      const int row = (i << 1) + (lane >> 5);
      f32x4 wv = *(const f32x4*)(Wlw +
          (((row << 9) + ((lane & 31) << 4)) ^ ((row & 7) << 4)));
      __builtin_nontemporal_store(wv,
          (f32x4*)(wb1 + ((size_t)row << 12) + (kt << 7) + ((lane & 31) << 2)));
    }
#pragma unroll
    for (int kk = 0; kk < 4; ++kk) {
      const int wbo = (lr << 9) + (kk << 7) + (lg << 5);
      f32x4 a0 = *(const f32x4*)(Wlw + (wbo ^ ((lr & 7) << 4)));
      f32x4 a1 = *(const f32x4*)(Wlw + ((wbo + 16) ^ ((lr & 7) << 4)));
      short8 ap;
      ap[0] = (short)f2bf(a0[0]); ap[1] = (short)f2bf(a0[1]);
      ap[2] = (short)f2bf(a0[2]); ap[3] = (short)f2bf(a0[3]);
      ap[4] = (short)f2bf(a1[0]); ap[5] = (short)f2bf(a1[1]);
      ap[6] = (short)f2bf(a1[2]); ap[7] = (short)f2bf(a1[3]);
#pragma unroll
      for (int cd = 0; cd < 4; ++cd) {
        const int drow = (cd << 4) + lr;
        short8 bv = *(const short8*)((const char*)Vl +
            ((drow * 256 + (kk << 6) + (lg << 4)) ^ ((drow & 7) << 4)));
        oacc[cd] = mfma_bf16(ap, bv, oacc[cd]);
      }
    }
    WG_BARRIER();
    if (kt < 31) {
#pragma unroll
      for (int i = 0; i < 4; ++i) {
        *(u32x4*)((char*)Kl + koff[i]) = rK[i];
        *(u32x4*)((char*)Vl + voff[i]) = rV[i];
      }
    }
    if (kt < 30) {
#pragma unroll
      for (int i = 0; i < 4; ++i) {
        rK[i] = *(const u32x4*)(kgbase + ((size_t)(kt + 2) << 13) + kgo[i]);
        rV[i] = *(const u32x4*)(vgbase + ((size_t)(kt + 2) << 7) + vgo[i]);
      }
    }
    WG_BARRIER();
  }
  // write O(t1)
#pragma unroll
  for (int cd = 0; cd < 4; ++cd)
#pragma unroll
    for (int i = 0; i < 4; ++i) {
      const int q = q0 + 64 + (wid << 4) + (lg << 2) + i;
      const int d = (cd << 4) + lr;
      __builtin_nontemporal_store(oacc[cd][i],
          outO + (((size_t)b * S_LEN + q) << 9) + h * 64 + d);
    }
}

extern "C" void kernel_launch(void* const* d_in, const int* in_sizes, int n_in,
                              void* d_out, int out_size, void* d_ws, size_t ws_size,
                              hipStream_t stream) {
  (void)in_sizes; (void)n_in; (void)out_size; (void)ws_size;
  const float* query = (const float*)d_in[0];
  const float* key_i = (const float*)d_in[1];
  const float* value = (const float*)d_in[2];
  const unsigned char* kpm = (const unsigned char*)d_in[3];
  const float* Wq = (const float*)d_in[4];
  const float* bq_ = (const float*)d_in[5];
  const float* Wk = (const float*)d_in[6];
  const float* bk_ = (const float*)d_in[7];
  const float* Wv = (const float*)d_in[8];
  const float* bv_ = (const float*)d_in[9];

  u16* Qp = (u16*)d_ws;                                  // [16][4096][64] bf16
  u16* Kp = Qp + (size_t)NB * NHD * S_LEN * 64;          // [16][4096][64] bf16
  u16* Vt = Kp + (size_t)NB * NHD * S_LEN * 64;          // [16][64][4096] bf16

  float* outO = (float*)d_out;
  float* outW = outO + (size_t)NB * S_LEN * HID;

  // fused Q/K/V projections: one launch, 768 blocks (3 blocks/CU)
  proj_kernel<<<dim3(64, 4, 3), dim3(256), 0, stream>>>(
      query, key_i, value, Wq, Wk, Wv, bq_, bk_, bv_, Qp, Kp, Vt);
  attn_kernel<<<dim3(512), dim3(256), 0, stream>>>(Qp, Kp, Vt, kpm, outO, outW);
}

// Round 9
// 306.829 us; speedup vs baseline: 1.3168x; 1.0290x over previous
//
#include <hip/hip_runtime.h>

typedef __attribute__((ext_vector_type(4))) float f32x4;
typedef __attribute__((ext_vector_type(8))) short short8;
typedef __attribute__((ext_vector_type(8))) __bf16 bf16x8;
typedef __attribute__((ext_vector_type(4))) unsigned int u32x4;
typedef __attribute__((ext_vector_type(4))) unsigned short u16x4;
typedef unsigned short u16;
typedef unsigned int u32;

#define NB 2
#define S_LEN 4096
#define NHD 8
#define HID 512

__device__ __forceinline__ u16 f2bf(float f) {
  u32 u = __builtin_bit_cast(u32, f);
  u += 0x7fffu + ((u >> 16) & 1u);   // round-to-nearest-even
  return (u16)(u >> 16);
}

// MFMA wrapper hedged over the two plausible builtin signatures (V8s vs V8y).
template <typename V>
static __device__ __forceinline__ auto mfma_imp(V a, V b, f32x4 c, int)
    -> decltype(__builtin_amdgcn_mfma_f32_16x16x32_bf16(a, b, c, 0, 0, 0)) {
  return __builtin_amdgcn_mfma_f32_16x16x32_bf16(a, b, c, 0, 0, 0);
}
template <typename V>
static __device__ __forceinline__ f32x4 mfma_imp(V a, V b, f32x4 c, long) {
  return __builtin_amdgcn_mfma_f32_16x16x32_bf16(
      __builtin_bit_cast(bf16x8, a), __builtin_bit_cast(bf16x8, b), c, 0, 0, 0);
}
static __device__ __forceinline__ f32x4 mfma_bf16(short8 a, short8 b, f32x4 c) {
  return mfma_imp(a, b, c, 0);
}

// Raw workgroup barrier that does NOT drain vmcnt: own LDS ops flushed
// (lgkmcnt 0), scheduler pinned (rule 18), then s_barrier. Global loads and
// the nontemporal W-store stream stay in flight across it.
#define WG_BARRIER()                                        \
  do {                                                      \
    asm volatile("s_waitcnt lgkmcnt(0)" ::: "memory");      \
    __builtin_amdgcn_sched_barrier(0);                      \
    __builtin_amdgcn_s_barrier();                           \
    __builtin_amdgcn_sched_barrier(0);                      \
  } while (0)

// ---------------------------------------------------------------------------
// Fused projection GEMM (Q, K, V in one launch via blockIdx.z):
// C[i][j] = sum_k X[i][k] * W[j][k] + bias[j], scaled, ->bf16
// z==0 (Q): out [(b*8+h)][s][64], scale 0.125 (1/sqrt(64) folded in)
// z==1 (K): out [(b*8+h)][s][64]
// z==2 (V): out [(b*8+h)][64][s]  (V^T so PV B-operand is contiguous)
// ---------------------------------------------------------------------------
__global__ __launch_bounds__(256, 2) void proj_kernel(
    const float* __restrict__ Xq, const float* __restrict__ Xk,
    const float* __restrict__ Xv, const float* __restrict__ Wq,
    const float* __restrict__ Wk, const float* __restrict__ Wv,
    const float* __restrict__ bq_, const float* __restrict__ bk_,
    const float* __restrict__ bv_, u16* __restrict__ oq,
    u16* __restrict__ ok, u16* __restrict__ ov)
{
  __shared__ u16 Al[128 * 64];
  __shared__ u16 Bl[128 * 64];
  const int z = blockIdx.z;
  const float* X = (z == 0) ? Xq : (z == 1) ? Xk : Xv;
  const float* W = (z == 0) ? Wq : (z == 1) ? Wk : Wv;
  const float* bias = (z == 0) ? bq_ : (z == 1) ? bk_ : bv_;
  u16* out = (z == 0) ? oq : (z == 1) ? ok : ov;
  const int transposeOut = (z == 2);
  const float scale = (z == 0) ? 0.125f : 1.0f;

  const int tid = threadIdx.x;
  const int lane = tid & 63;
  const int wid = tid >> 6;
  const int wr = (wid >> 1) << 6;
  const int wc = (wid & 1) << 6;
  const int bm = blockIdx.x << 7;
  const int bn = blockIdx.y << 7;

  f32x4 acc[4][4] = {};

#pragma unroll 1
  for (int k0 = 0; k0 < HID; k0 += 64) {
    __syncthreads();
#pragma unroll
    for (int i = 0; i < 4; ++i) {
      const int idx = i * 256 + tid;
      const int row = idx >> 3;     // 8 chunks of 8 elems per 64-wide row
      const int c = idx & 7;
      const int off = (row * 128 + c * 16) ^ ((row & 7) << 4);
      const float* ga = X + (size_t)(bm + row) * HID + k0 + c * 8;
      f32x4 a0 = *(const f32x4*)ga;
      f32x4 a1 = *(const f32x4*)(ga + 4);
      short8 pa;
      pa[0] = (short)f2bf(a0[0]); pa[1] = (short)f2bf(a0[1]);
      pa[2] = (short)f2bf(a0[2]); pa[3] = (short)f2bf(a0[3]);
      pa[4] = (short)f2bf(a1[0]); pa[5] = (short)f2bf(a1[1]);
      pa[6] = (short)f2bf(a1[2]); pa[7] = (short)f2bf(a1[3]);
      *(short8*)((char*)Al + off) = pa;
      const float* gb = W + (size_t)(bn + row) * HID + k0 + c * 8;
      f32x4 b0 = *(const f32x4*)gb;
      f32x4 b1 = *(const f32x4*)(gb + 4);
      short8 pb;
      pb[0] = (short)f2bf(b0[0]); pb[1] = (short)f2bf(b0[1]);
      pb[2] = (short)f2bf(b0[2]); pb[3] = (short)f2bf(b0[3]);
      pb[4] = (short)f2bf(b1[0]); pb[5] = (short)f2bf(b1[1]);
      pb[6] = (short)f2bf(b1[2]); pb[7] = (short)f2bf(b1[3]);
      *(short8*)((char*)Bl + off) = pb;
    }
    __syncthreads();
#pragma unroll
    for (int ks = 0; ks < 2; ++ks) {
      const int koffb = (ks * 32 + ((lane >> 4) << 3)) * 2;
      short8 af[4], bfr[4];
#pragma unroll
      for (int m = 0; m < 4; ++m) {
        const int row = wr + m * 16 + (lane & 15);
        af[m] = *(const short8*)((const char*)Al + ((row * 128 + koffb) ^ ((row & 7) << 4)));
      }
#pragma unroll
      for (int n = 0; n < 4; ++n) {
        const int row = wc + n * 16 + (lane & 15);
        bfr[n] = *(const short8*)((const char*)Bl + ((row * 128 + koffb) ^ ((row & 7) << 4)));
      }
#pragma unroll
      for (int m = 0; m < 4; ++m)
#pragma unroll
        for (int n = 0; n < 4; ++n)
          acc[m][n] = mfma_bf16(af[m], bfr[n], acc[m][n]);
    }
  }

#pragma unroll
  for (int n = 0; n < 4; ++n) {
    const int j = bn + wc + n * 16 + (lane & 15);
    const float bj = bias[j];
    const int h = j >> 6, d = j & 63;
#pragma unroll
    for (int m = 0; m < 4; ++m) {
      const int rbase = bm + wr + m * 16 + ((lane >> 4) << 2);
      const int b = rbase >> 12;
      const int s = rbase & (S_LEN - 1);
      if (!transposeOut) {
#pragma unroll
        for (int i = 0; i < 4; ++i) {
          const float v = (acc[m][n][i] + bj) * scale;
          out[(((size_t)(b * NHD + h) * S_LEN + (s + i)) << 6) + d] = f2bf(v);
        }
      } else {
        u16x4 pk;
#pragma unroll
        for (int i = 0; i < 4; ++i) pk[i] = f2bf((acc[m][n][i] + bj) * scale);
        *(u16x4*)(out + (((size_t)(b * NHD + h) * 64 + d) << 12) + s) = pk;
      }
    }
  }
}

// ---------------------------------------------------------------------------
// Fused attention, q-tile-pair pipelined + LDS-transposed W stores.
// (Best verified structure — 307.5 us. Rounds 5-7 established empirically:
//  2 blocks/CU required; K AND V staged in LDS required; 2-barrier pipelined
//  rounds with non-draining barriers are optimal for all phases.)
// One WG per (b*8+h, 128 q-rows) = two 64-row tiles t0,t1; 4 waves x 16
// q-rows per tile. Phases: A0 (denominators t0), phase1 (B t0 + A t1),
// phase2 (B t1) — pipelined staging, non-draining barriers.
// Normalized fp32 P goes to a per-wave LDS buffer Wl (swizzled), then is
// read back ROW-MAJOR and nt-stored as 8x 1-KB instructions covering
// contiguous 512-B row segments. PV reads fp32 from Wl and converts to
// bf16 in-register.
// ---------------------------------------------------------------------------
__global__ __launch_bounds__(256, 2) void attn_kernel(
    const u16* __restrict__ Qp, const u16* __restrict__ Kp,
    const u16* __restrict__ Vt, const unsigned char* __restrict__ mask,
    float* __restrict__ outO, float* __restrict__ outW)
{
  __shared__ u16 Kl[128 * 64];        // K tile (16 KB)
  __shared__ u16 Vl[64 * 128];        // V^T tile (16 KB)
  __shared__ float Wl[4][16 * 128];   // per-wave fp32 normalized P (32 KB)
  __shared__ u32 anyMaskSh;

  const int tid = threadIdx.x;
  const int lane = tid & 63;
  const int wid = tid >> 6;
  const int lr = lane & 15;
  const int lg = lane >> 4;

  // XCD-bijective swizzle: 512 blocks; each XCD gets a 64-block chunk = 2
  // heads (K+V+Q = 3 MB fits the 4 MB per-XCD L2).
  const int bid = blockIdx.x;
  const int swz = (bid & 7) * 64 + (bid >> 3);
  const int bh = swz >> 5;          // b*8 + h
  const int q0 = (swz & 31) << 7;   // 128 q-rows = tiles t0,t1
  const int b = bh >> 3;
  const int h = bh & 7;

  char* const Wlw = (char*)Wl[wid];

  // per-thread staging offsets (K tile: [128][64]; V tile: [64][128] keys)
  int koff[4], kgo[4], voff[4], vgo[4];
#pragma unroll
  for (int i = 0; i < 4; ++i) {
    const int idx = i * 256 + tid;
    const int kr = idx >> 3, kc = idx & 7;
    koff[i] = (kr * 128 + kc * 16) ^ ((kr & 7) << 4);
    kgo[i] = (kr << 6) + kc * 8;
    const int vr = idx >> 4, vc = idx & 15;
    voff[i] = (vr * 256 + vc * 16) ^ ((vr & 7) << 4);
    vgo[i] = (vr << 12) + vc * 8;
  }
  const u16* kgbase = Kp + ((size_t)bh << 18);
  const u16* vgbase = Vt + ((size_t)bh << 18);

  if (tid == 0) anyMaskSh = 0u;
  __syncthreads();
  {
    u32x4 mv = *(const u32x4*)(mask + (size_t)b * S_LEN + tid * 16);
    if (mv[0] | mv[1] | mv[2] | mv[3]) atomicOr(&anyMaskSh, 1u);
  }
  __syncthreads();
  const bool anyMask = (anyMaskSh != 0u);

  // Q fragments (MFMA B operand) for both tiles, straight from global (one-time)
  short8 bq[2][2];
#pragma unroll
  for (int t = 0; t < 2; ++t)
#pragma unroll
    for (int ks = 0; ks < 2; ++ks) {
      const int qr = q0 + (t << 6) + (wid << 4) + lr;
      bq[t][ks] = *(const short8*)(
          Qp + (((size_t)bh * S_LEN + qr) << 6) + ks * 32 + lg * 8);
    }

  const unsigned char* mrow = mask + (size_t)b * S_LEN + (lg << 2);
  u32x4 rK[4], rV[4];

  // ---------------- phase A0: denominators for t0 ----------------
#pragma unroll
  for (int i = 0; i < 4; ++i) rK[i] = *(const u32x4*)(kgbase + kgo[i]);
#pragma unroll
  for (int i = 0; i < 4; ++i) *(u32x4*)((char*)Kl + koff[i]) = rK[i];
#pragma unroll
  for (int i = 0; i < 4; ++i) rK[i] = *(const u32x4*)(kgbase + (1 << 13) + kgo[i]);
  WG_BARRIER();

  float lsum0 = 0.f;
#pragma unroll 1
  for (int kt = 0; kt < 32; ++kt) {
#pragma unroll
    for (int rb = 0; rb < 8; ++rb) {
      const int krow = (rb << 4) + lr;
      short8 ak0 = *(const short8*)((const char*)Kl +
          ((krow * 128 + (lg << 4)) ^ ((krow & 7) << 4)));
      short8 ak1 = *(const short8*)((const char*)Kl +
          ((krow * 128 + 64 + (lg << 4)) ^ ((krow & 7) << 4)));
      u32 mw = 0u;
      if (anyMask) mw = *(const u32*)(mrow + (kt << 7) + (rb << 4));
      f32x4 sv = {};
      sv = mfma_bf16(ak0, bq[0][0], sv);
      sv = mfma_bf16(ak1, bq[0][1], sv);
      float p0 = __expf(sv[0]);
      float p1 = __expf(sv[1]);
      float p2 = __expf(sv[2]);
      float p3 = __expf(sv[3]);
      if (mw) {
        if (mw & 0x000000FFu) p0 = 0.f;
        if (mw & 0x0000FF00u) p1 = 0.f;
        if (mw & 0x00FF0000u) p2 = 0.f;
        if (mw & 0xFF000000u) p3 = 0.f;
      }
      lsum0 += (p0 + p1) + (p2 + p3);
    }
    WG_BARRIER();
    if (kt < 31) {
#pragma unroll
      for (int i = 0; i < 4; ++i) *(u32x4*)((char*)Kl + koff[i]) = rK[i];
    }
    if (kt < 30) {
#pragma unroll
      for (int i = 0; i < 4; ++i)
        rK[i] = *(const u32x4*)(kgbase + ((size_t)(kt + 2) << 13) + kgo[i]);
    }
    WG_BARRIER();
  }
  float inv0;
  {
    float t = lsum0;
    t += __shfl_xor(t, 16);
    t += __shfl_xor(t, 32);
    inv0 = 1.0f / t;
  }

  // ---------------- phase 1: B(t0) + A(t1) ----------------
#pragma unroll
  for (int i = 0; i < 4; ++i) {
    rK[i] = *(const u32x4*)(kgbase + kgo[i]);
    rV[i] = *(const u32x4*)(vgbase + vgo[i]);
  }
#pragma unroll
  for (int i = 0; i < 4; ++i) {
    *(u32x4*)((char*)Kl + koff[i]) = rK[i];
    *(u32x4*)((char*)Vl + voff[i]) = rV[i];
  }
#pragma unroll
  for (int i = 0; i < 4; ++i) {
    rK[i] = *(const u32x4*)(kgbase + (1 << 13) + kgo[i]);
    rV[i] = *(const u32x4*)(vgbase + (1 << 7) + vgo[i]);
  }
  WG_BARRIER();

  float lsum1 = 0.f;
  f32x4 oacc[4] = {};
  float* const wb0 = outW + ((size_t)(bh * S_LEN + q0 + (wid << 4)) << 12);
#pragma unroll 1
  for (int kt = 0; kt < 32; ++kt) {
#pragma unroll
    for (int rb = 0; rb < 8; ++rb) {
      const int krow = (rb << 4) + lr;
      short8 ak0 = *(const short8*)((const char*)Kl +
          ((krow * 128 + (lg << 4)) ^ ((krow & 7) << 4)));
      short8 ak1 = *(const short8*)((const char*)Kl +
          ((krow * 128 + 64 + (lg << 4)) ^ ((krow & 7) << 4)));
      u32 mw = 0u;
      if (anyMask) mw = *(const u32*)(mrow + (kt << 7) + (rb << 4));
      // B for t0: normalized fp32 P -> Wl (swizzled)
      {
        f32x4 sv = {};
        sv = mfma_bf16(ak0, bq[0][0], sv);
        sv = mfma_bf16(ak1, bq[0][1], sv);
        float p0 = __expf(sv[0]) * inv0;
        float p1 = __expf(sv[1]) * inv0;
        float p2 = __expf(sv[2]) * inv0;
        float p3 = __expf(sv[3]) * inv0;
        if (mw) {
          if (mw & 0x000000FFu) p0 = 0.f;
          if (mw & 0x0000FF00u) p1 = 0.f;
          if (mw & 0x00FF0000u) p2 = 0.f;
          if (mw & 0xFF000000u) p3 = 0.f;
        }
        f32x4 wv; wv[0] = p0; wv[1] = p1; wv[2] = p2; wv[3] = p3;
        *(f32x4*)(Wlw + (((lr << 9) + (rb << 6) + (lg << 4)) ^ ((lr & 7) << 4))) = wv;
      }
      // A for t1 (same ak fragments — K rows are q-independent)
      {
        f32x4 sv = {};
        sv = mfma_bf16(ak0, bq[1][0], sv);
        sv = mfma_bf16(ak1, bq[1][1], sv);
        float p0 = __expf(sv[0]);
        float p1 = __expf(sv[1]);
        float p2 = __expf(sv[2]);
        float p3 = __expf(sv[3]);
        if (mw) {
          if (mw & 0x000000FFu) p0 = 0.f;
          if (mw & 0x0000FF00u) p1 = 0.f;
          if (mw & 0x00FF0000u) p2 = 0.f;
          if (mw & 0xFF000000u) p3 = 0.f;
        }
        lsum1 += (p0 + p1) + (p2 + p3);
      }
    }
    // store-out: read Wl row-major, 8x 1-KB nt stores (2x contiguous 512 B)
#pragma unroll
    for (int i = 0; i < 8; ++i) {
      const int row = (i << 1) + (lane >> 5);
      f32x4 wv = *(const f32x4*)(Wlw +
          (((row << 9) + ((lane & 31) << 4)) ^ ((row & 7) << 4)));
      __builtin_nontemporal_store(wv,
          (f32x4*)(wb0 + ((size_t)row << 12) + (kt << 7) + ((lane & 31) << 2)));
    }
    // PV for t0: read fp32 P from Wl (same-wave RAW), convert to bf16
#pragma unroll
    for (int kk = 0; kk < 4; ++kk) {
      const int wbo = (lr << 9) + (kk << 7) + (lg << 5);
      f32x4 a0 = *(const f32x4*)(Wlw + (wbo ^ ((lr & 7) << 4)));
      f32x4 a1 = *(const f32x4*)(Wlw + ((wbo + 16) ^ ((lr & 7) << 4)));
      short8 ap;
      ap[0] = (short)f2bf(a0[0]); ap[1] = (short)f2bf(a0[1]);
      ap[2] = (short)f2bf(a0[2]); ap[3] = (short)f2bf(a0[3]);
      ap[4] = (short)f2bf(a1[0]); ap[5] = (short)f2bf(a1[1]);
      ap[6] = (short)f2bf(a1[2]); ap[7] = (short)f2bf(a1[3]);
#pragma unroll
      for (int cd = 0; cd < 4; ++cd) {
        const int drow = (cd << 4) + lr;
        short8 bv = *(const short8*)((const char*)Vl +
            ((drow * 256 + (kk << 6) + (lg << 4)) ^ ((drow & 7) << 4)));
        oacc[cd] = mfma_bf16(ap, bv, oacc[cd]);
      }
    }
    WG_BARRIER();
    if (kt < 31) {
#pragma unroll
      for (int i = 0; i < 4; ++i) {
        *(u32x4*)((char*)Kl + koff[i]) = rK[i];
        *(u32x4*)((char*)Vl + voff[i]) = rV[i];
      }
    }
    if (kt < 30) {
#pragma unroll
      for (int i = 0; i < 4; ++i) {
        rK[i] = *(const u32x4*)(kgbase + ((size_t)(kt + 2) << 13) + kgo[i]);
        rV[i] = *(const u32x4*)(vgbase + ((size_t)(kt + 2) << 7) + vgo[i]);
      }
    }
    WG_BARRIER();
  }
  float inv1;
  {
    float t = lsum1;
    t += __shfl_xor(t, 16);
    t += __shfl_xor(t, 32);
    inv1 = 1.0f / t;
  }
  // write O(t0); free oacc for t1
#pragma unroll
  for (int cd = 0; cd < 4; ++cd)
#pragma unroll
    for (int i = 0; i < 4; ++i) {
      const int q = q0 + (wid << 4) + (lg << 2) + i;
      const int d = (cd << 4) + lr;
      __builtin_nontemporal_store(oacc[cd][i],
          outO + (((size_t)b * S_LEN + q) << 9) + h * 64 + d);
      oacc[cd][i] = 0.f;
    }

  // ---------------- phase 2: B(t1) ----------------
#pragma unroll
  for (int i = 0; i < 4; ++i) {
    rK[i] = *(const u32x4*)(kgbase + kgo[i]);
    rV[i] = *(const u32x4*)(vgbase + vgo[i]);
  }
#pragma unroll
  for (int i = 0; i < 4; ++i) {
    *(u32x4*)((char*)Kl + koff[i]) = rK[i];
    *(u32x4*)((char*)Vl + voff[i]) = rV[i];
  }
#pragma unroll
  for (int i = 0; i < 4; ++i) {
    rK[i] = *(const u32x4*)(kgbase + (1 << 13) + kgo[i]);
    rV[i] = *(const u32x4*)(vgbase + (1 << 7) + vgo[i]);
  }
  WG_BARRIER();

  float* const wb1 = outW + ((size_t)(bh * S_LEN + q0 + 64 + (wid << 4)) << 12);
#pragma unroll 1
  for (int kt = 0; kt < 32; ++kt) {
#pragma unroll
    for (int rb = 0; rb < 8; ++rb) {
      const int krow = (rb << 4) + lr;
      short8 ak0 = *(const short8*)((const char*)Kl +
          ((krow * 128 + (lg << 4)) ^ ((krow & 7) << 4)));
      short8 ak1 = *(const short8*)((const char*)Kl +
          ((krow * 128 + 64 + (lg << 4)) ^ ((krow & 7) << 4)));
      u32 mw = 0u;
      if (anyMask) mw = *(const u32*)(mrow + (kt << 7) + (rb << 4));
      f32x4 sv = {};
      sv = mfma_bf16(ak0, bq[1][0], sv);
      sv = mfma_bf16(ak1, bq[1][1], sv);
      float p0 = __expf(sv[0]) * inv1;
      float p1 = __expf(sv[1]) * inv1;
      float p2 = __expf(sv[2]) * inv1;
      float p3 = __expf(sv[3]) * inv1;
      if (mw) {
        if (mw & 0x000000FFu) p0 = 0.f;
        if (mw & 0x0000FF00u) p1 = 0.f;
        if (mw & 0x00FF0000u) p2 = 0.f;
        if (mw & 0xFF000000u) p3 = 0.f;
      }
      f32x4 wv; wv[0] = p0; wv[1] = p1; wv[2] = p2; wv[3] = p3;
      *(f32x4*)(Wlw + (((lr << 9) + (rb << 6) + (lg << 4)) ^ ((lr & 7) << 4))) = wv;
    }
#pragma unroll
    for (int i = 0; i < 8; ++i) {
      const int row = (i << 1) + (lane >> 5);
      f32x4 wv = *(const f32x4*)(Wlw +
          (((row << 9) + ((lane & 31) << 4)) ^ ((row & 7) << 4)));
      __builtin_nontemporal_store(wv,
          (f32x4*)(wb1 + ((size_t)row << 12) + (kt << 7) + ((lane & 31) << 2)));
    }
#pragma unroll
    for (int kk = 0; kk < 4; ++kk) {
      const int wbo = (lr << 9) + (kk << 7) + (lg << 5);
      f32x4 a0 = *(const f32x4*)(Wlw + (wbo ^ ((lr & 7) << 4)));
      f32x4 a1 = *(const f32x4*)(Wlw + ((wbo + 16) ^ ((lr & 7) << 4)));
      short8 ap;
      ap[0] = (short)f2bf(a0[0]); ap[1] = (short)f2bf(a0[1]);
      ap[2] = (short)f2bf(a0[2]); ap[3] = (short)f2bf(a0[3]);
      ap[4] = (short)f2bf(a1[0]); ap[5] = (short)f2bf(a1[1]);
      ap[6] = (short)f2bf(a1[2]); ap[7] = (short)f2bf(a1[3]);
#pragma unroll
      for (int cd = 0; cd < 4; ++cd) {
        const int drow = (cd << 4) + lr;
        short8 bv = *(const short8*)((const char*)Vl +
            ((drow * 256 + (kk << 6) + (lg << 4)) ^ ((drow & 7) << 4)));
        oacc[cd] = mfma_bf16(ap, bv, oacc[cd]);
      }
    }
    WG_BARRIER();
    if (kt < 31) {
#pragma unroll
      for (int i = 0; i < 4; ++i) {
        *(u32x4*)((char*)Kl + koff[i]) = rK[i];
        *(u32x4*)((char*)Vl + voff[i]) = rV[i];
      }
    }
    if (kt < 30) {
#pragma unroll
      for (int i = 0; i < 4; ++i) {
        rK[i] = *(const u32x4*)(kgbase + ((size_t)(kt + 2) << 13) + kgo[i]);
        rV[i] = *(const u32x4*)(vgbase + ((size_t)(kt + 2) << 7) + vgo[i]);
      }
    }
    WG_BARRIER();
  }
  // write O(t1)
#pragma unroll
  for (int cd = 0; cd < 4; ++cd)
#pragma unroll
    for (int i = 0; i < 4; ++i) {
      const int q = q0 + 64 + (wid << 4) + (lg << 2) + i;
      const int d = (cd << 4) + lr;
      __builtin_nontemporal_store(oacc[cd][i],
          outO + (((size_t)b * S_LEN + q) << 9) + h * 64 + d);
    }
}

extern "C" void kernel_launch(void* const* d_in, const int* in_sizes, int n_in,
                              void* d_out, int out_size, void* d_ws, size_t ws_size,
                              hipStream_t stream) {
  (void)in_sizes; (void)n_in; (void)out_size; (void)ws_size;
  const float* query = (const float*)d_in[0];
  const float* key_i = (const float*)d_in[1];
  const float* value = (const float*)d_in[2];
  const unsigned char* kpm = (const unsigned char*)d_in[3];
  const float* Wq = (const float*)d_in[4];
  const float* bq_ = (const float*)d_in[5];
  const float* Wk = (const float*)d_in[6];
  const float* bk_ = (const float*)d_in[7];
  const float* Wv = (const float*)d_in[8];
  const float* bv_ = (const float*)d_in[9];

  u16* Qp = (u16*)d_ws;                                  // [16][4096][64] bf16
  u16* Kp = Qp + (size_t)NB * NHD * S_LEN * 64;          // [16][4096][64] bf16
  u16* Vt = Kp + (size_t)NB * NHD * S_LEN * 64;          // [16][64][4096] bf16

  float* outO = (float*)d_out;
  float* outW = outO + (size_t)NB * S_LEN * HID;

  // fused Q/K/V projections: one launch, 768 blocks (3 blocks/CU)
  proj_kernel<<<dim3(64, 4, 3), dim3(256), 0, stream>>>(
      query, key_i, value, Wq, Wk, Wv, bq_, bk_, bv_, Qp, Kp, Vt);
  attn_kernel<<<dim3(512), dim3(256), 0, stream>>>(Qp, Kp, Vt, kpm, outO, outW);
}